// Round 1
// baseline (654.675 us; speedup 1.0000x reference)
//
#include <hip/hip_runtime.h>
#include <hip/hip_bf16.h>

#define N_IMG 2
#define HH 256
#define WW 256
#define HW 65536
#define PRE 1024
#define POST 256
#define NBIN 4096
#define CAPC 8192
#define NMS_THR 0.7f
#define SCORE_T 0.1f
#define MIN_SZ 4.0f

// ---------- sortable key helpers ----------
__device__ __forceinline__ unsigned int fkey(float f) {
    unsigned int u = __float_as_uint(f);
    return u ^ ((u & 0x80000000u) ? 0xFFFFFFFFu : 0x80000000u);
}
__device__ __forceinline__ float unfkey(unsigned int k) {
    unsigned int u = (k & 0x80000000u) ? (k ^ 0x80000000u) : ~k;
    return __uint_as_float(u);
}

// ---------- kernels ----------
__global__ void k_init(unsigned int* hist, unsigned int* ccnt) {
    int t = blockIdx.x * blockDim.x + threadIdx.x;
    if (t < N_IMG * NBIN) hist[t] = 0u;
    if (t < N_IMG) ccnt[t] = 0u;
}

__global__ void k_hist(const float* __restrict__ obj, unsigned int* hist) {
    int g = blockIdx.x * blockDim.x + threadIdx.x;   // 0 .. N_IMG*HW-1
    int img = g >> 16;
    unsigned int key = fkey(obj[g]);
    atomicAdd(&hist[img * NBIN + (key >> 20)], 1u);
}

__global__ void k_findbin(const unsigned int* __restrict__ hist, unsigned int* selB) {
    __shared__ unsigned int lh[NBIN];
    __shared__ unsigned int chunk[256];
    int img = blockIdx.x;
    int t = threadIdx.x;
    unsigned int s = 0;
    for (int k = 0; k < 16; ++k) {
        unsigned int v = hist[img * NBIN + t * 16 + k];
        lh[t * 16 + k] = v;
        s += v;
    }
    chunk[t] = s;
    __syncthreads();
    if (t == 0) {
        unsigned int run = 0;
        int c;
        for (c = 255; c >= 0; --c) {
            if (run + chunk[c] >= PRE) break;
            run += chunk[c];
        }
        unsigned int B = 0;
        for (int b = c * 16 + 15; b >= c * 16; --b) {
            if (run + lh[b] >= PRE) { B = (unsigned int)b; break; }
            run += lh[b];
        }
        selB[img] = B;
    }
}

__global__ void k_compact(const float* __restrict__ obj, const unsigned int* __restrict__ selB,
                          unsigned int* ccnt, unsigned long long* cbuf) {
    int g = blockIdx.x * blockDim.x + threadIdx.x;
    int img = g >> 16;
    int e = g & 0xFFFF;
    unsigned int key = fkey(obj[g]);
    if ((key >> 20) >= selB[img]) {
        unsigned int pos = atomicAdd(&ccnt[img], 1u);
        if (pos < CAPC) {
            cbuf[img * CAPC + pos] =
                ((unsigned long long)key << 32) | (unsigned long long)(0xFFFFFFFFu - (unsigned int)e);
        }
    }
}

__global__ __launch_bounds__(1024) void k_sort(const unsigned int* __restrict__ ccnt,
                                               const unsigned long long* __restrict__ cbuf,
                                               unsigned int* tidx, float* tscr) {
    __shared__ unsigned long long sk[CAPC];   // 64 KB
    int img = blockIdx.x;
    int t = threadIdx.x;
    unsigned int M = ccnt[img];
    if (M > CAPC) M = CAPC;
    for (int i = t; i < CAPC; i += 1024) sk[i] = (i < (int)M) ? cbuf[img * CAPC + i] : 0ULL;
    __syncthreads();
    for (int k = 2; k <= CAPC; k <<= 1) {
        for (int j = k >> 1; j > 0; j >>= 1) {
            for (int i = t; i < CAPC; i += 1024) {
                int ixj = i ^ j;
                if (ixj > i) {
                    unsigned long long a = sk[i], b = sk[ixj];
                    bool up = ((i & k) == 0);
                    if (up ? (a < b) : (a > b)) { sk[i] = b; sk[ixj] = a; }
                }
            }
            __syncthreads();
        }
    }
    if (t < PRE) {
        unsigned long long v = sk[t];
        unsigned int key = (unsigned int)(v >> 32);
        unsigned int idx = 0xFFFFFFFFu - (unsigned int)(v & 0xFFFFFFFFULL);
        tidx[img * PRE + t] = idx;
        tscr[img * PRE + t] = unfkey(key);
    }
}

__global__ __launch_bounds__(1024) void k_decode(const float* __restrict__ boxreg,
                                                 const unsigned int* __restrict__ tidx,
                                                 const float* __restrict__ tscr,
                                                 float* boxes, float* corn, float* area, float* rad,
                                                 unsigned long long* vmask) {
    int img = blockIdx.x;
    int r = threadIdx.x;
    unsigned int idx = tidx[img * PRE + r];
    float sc = tscr[img * PRE + r];
    int h = (int)(idx >> 8);
    int w = (int)(idx & 255u);
    const float* rg = boxreg + (size_t)img * 5 * HW;
    float t_ = rg[0 * HW + idx] * 1024.0f;
    float rr = rg[1 * HW + idx] * 1024.0f;
    float bb = rg[2 * HW + idx] * 1024.0f;
    float ll = rg[3 * HW + idx] * 1024.0f;
    float ang = (rg[4 * HW + idx] - 0.5f) * 90.0f;
    float wd = ll + rr;
    float ht = t_ + bb;
    float xc = (float)w * 4.0f + 0.5f * (rr - ll);
    float yc = (float)h * 4.0f + 0.5f * (bb - t_);
    xc = fminf(fmaxf(xc, 0.0f), 1023.0f);
    yc = fminf(fmaxf(yc, 0.0f), 1023.0f);
    bool valid = (sc > SCORE_T) && (wd >= MIN_SZ) && (ht >= MIN_SZ);

    float* bx = boxes + (size_t)(img * PRE + r) * 5;
    bx[0] = xc; bx[1] = yc; bx[2] = wd; bx[3] = ht; bx[4] = ang;

    float th = ang * (float)(3.14159265358979323846 / 180.0);
    float c = cosf(th), s = sinf(th);
    const float dxs[4] = {-0.5f, 0.5f, 0.5f, -0.5f};
    const float dys[4] = {-0.5f, -0.5f, 0.5f, 0.5f};
    float* cr = corn + (size_t)(img * PRE + r) * 8;
#pragma unroll
    for (int k = 0; k < 4; ++k) {
        float dx = dxs[k] * wd, dy = dys[k] * ht;
        cr[2 * k]     = xc + dx * c - dy * s;
        cr[2 * k + 1] = yc + dx * s + dy * c;
    }
    area[img * PRE + r] = wd * ht;
    rad[img * PRE + r] = 0.5f * sqrtf(wd * wd + ht * ht) + 0.01f;  // tiny safety margin

    unsigned long long bal = __ballot(valid ? 1 : 0);
    if ((threadIdx.x & 63) == 0) vmask[img * 16 + (threadIdx.x >> 6)] = bal;
}

// Sutherland-Hodgman convex clip of quad A against quad B edges; mirrors reference math.
__device__ float inter_area(const float* pax, const float* pay, const float* __restrict__ cb) {
    float px[8], py[8], qx[8], qy[8];
    int n = 4;
#pragma unroll
    for (int k = 0; k < 4; ++k) { px[k] = pax[k]; py[k] = pay[k]; }
    for (int e = 0; e < 4; ++e) {
        float p1x = cb[2 * e], p1y = cb[2 * e + 1];
        int e2 = (e + 1) & 3;
        float ex = cb[2 * e2] - p1x, ey = cb[2 * e2 + 1] - p1y;
        int m = 0;
        for (int k = 0; k < n; ++k) {
            int kn = (k + 1 < n) ? k + 1 : 0;
            float dc = ex * (py[k] - p1y) - ey * (px[k] - p1x);
            float dn = ex * (py[kn] - p1y) - ey * (px[kn] - p1x);
            bool ic = dc >= 0.0f;
            bool inx = dn >= 0.0f;
            if (ic && m < 8) { qx[m] = px[k]; qy[m] = py[k]; ++m; }
            if ((ic != inx) && m < 8) {
                float den = dc - dn;
                float safe = (fabsf(den) > 1e-9f) ? den : 1.0f;
                float tt = dc / safe;
                qx[m] = px[k] + tt * (px[kn] - px[k]);
                qy[m] = py[k] + tt * (py[kn] - py[k]);
                ++m;
            }
        }
        n = m;
        for (int k = 0; k < n; ++k) { px[k] = qx[k]; py[k] = qy[k]; }
    }
    if (n < 3) return 0.0f;
    float s = 0.0f;
    for (int k = 0; k < n; ++k) {
        int kn = (k + 1 < n) ? k + 1 : 0;
        s += px[k] * py[kn] - px[kn] * py[k];
    }
    return 0.5f * fabsf(s);
}

__global__ __launch_bounds__(256) void k_iou(const float* __restrict__ boxes,
                                             const float* __restrict__ corn,
                                             const float* __restrict__ area,
                                             const float* __restrict__ rad,
                                             unsigned long long* masks) {
    int row = blockIdx.x;          // 0 .. N_IMG*PRE-1
    int img = row >> 10;
    int i = row & 1023;
    __shared__ float pax[4], pay[4], sArA, sCxA, sCyA, sRA;
    if (threadIdx.x == 0) {
        const float* cr = corn + (size_t)row * 8;
#pragma unroll
        for (int k = 0; k < 4; ++k) { pax[k] = cr[2 * k]; pay[k] = cr[2 * k + 1]; }
        sArA = area[row];
        const float* b = boxes + (size_t)row * 5;
        sCxA = b[0]; sCyA = b[1];
        sRA = rad[row];
    }
    __syncthreads();
    for (int c = 0; c < 4; ++c) {
        int j = c * 256 + threadIdx.x;
        bool flag = false;
        if (j > i) {
            int col = img * PRE + j;
            float dx = boxes[(size_t)col * 5 + 0] - sCxA;
            float dy = boxes[(size_t)col * 5 + 1] - sCyA;
            float rr = sRA + rad[col];
            if (dx * dx + dy * dy <= rr * rr) {
                const float* cbp = corn + (size_t)col * 8;
                float inter = inter_area(pax, pay, cbp);
                float uni = sArA + area[col] - inter;
                float iou = inter / fmaxf(uni, 1e-9f);
                flag = iou > NMS_THR;
            }
        }
        unsigned long long bal = __ballot(flag ? 1 : 0);
        if ((threadIdx.x & 63) == 0)
            masks[(size_t)row * 16 + c * 4 + (threadIdx.x >> 6)] = bal;
    }
}

__global__ void k_nms(const unsigned long long* __restrict__ masks,
                      const unsigned long long* __restrict__ vmask,
                      unsigned int* kept, unsigned int* kcnt) {
    int img = blockIdx.x;
    int lane = threadIdx.x;                 // 0..63, one wave
    unsigned long long sup = 0ULL;
    unsigned long long vw = (lane < 16) ? vmask[img * 16 + lane] : 0ULL;
    int count = 0;
    for (int i = 0; i < PRE; ++i) {
        int owner = i >> 6;
        int bit = i & 63;
        int my = (int)((vw >> bit) & 1ULL) & (int)((~sup >> bit) & 1ULL);
        int kflag = __shfl(my, owner, 64);
        if (kflag) {
            if (lane < 16) sup |= masks[(size_t)(img * PRE + i) * 16 + lane];
            if (lane == 0 && count < POST) kept[img * POST + count] = (unsigned int)i;
            ++count;
        }
    }
    if (lane == 0) kcnt[img] = (count > POST) ? POST : (unsigned int)count;
}

__global__ void k_out(const float* __restrict__ boxes, const float* __restrict__ tscr,
                      const unsigned int* __restrict__ kept, const unsigned int* __restrict__ kcnt,
                      float* __restrict__ out) {
    int img = blockIdx.x;
    int r = threadIdx.x;
    float v[6] = {0.f, 0.f, 0.f, 0.f, 0.f, 0.f};
    unsigned int cnt = kcnt[img];
    if (r < (int)cnt) {
        unsigned int i = kept[img * POST + r];
        const float* b = boxes + (size_t)(img * PRE + i) * 5;
        v[0] = b[0]; v[1] = b[1]; v[2] = b[2]; v[3] = b[3]; v[4] = b[4];
        v[5] = tscr[img * PRE + i];
    }
    float* o = out + (size_t)(img * POST + r) * 6;
#pragma unroll
    for (int k = 0; k < 6; ++k) o[k] = v[k];
}

// ---------- workspace layout (all offsets 8-byte aligned) ----------
enum : size_t {
    OFF_HIST = 0,          // 2*4096*4  = 32768
    OFF_CCNT = 32768,      // 8
    OFF_SELB = 32776,      // 8
    OFF_CBUF = 32784,      // 2*8192*8  = 131072 -> 163856
    OFF_TIDX = 163856,     // 8192 -> 172048
    OFF_TSCR = 172048,     // 8192 -> 180240
    OFF_BOX  = 180240,     // 40960 -> 221200
    OFF_CORN = 221200,     // 65536 -> 286736
    OFF_AREA = 286736,     // 8192 -> 294928
    OFF_RAD  = 294928,     // 8192 -> 303120
    OFF_VMSK = 303120,     // 256 -> 303376
    OFF_MASK = 303376,     // 262144 -> 565520
    OFF_KEPT = 565520,     // 2048 -> 567568
    OFF_KCNT = 567568,     // 8 -> 567576
};

extern "C" void kernel_launch(void* const* d_in, const int* in_sizes, int n_in,
                              void* d_out, int out_size, void* d_ws, size_t ws_size,
                              hipStream_t stream) {
    const float* obj = (const float*)d_in[0];       // (2,1,256,256) f32
    const float* boxreg = (const float*)d_in[1];    // (2,5,256,256) f32
    float* out = (float*)d_out;                     // (2,256,6) f32

    char* w = (char*)d_ws;
    unsigned int* hist = (unsigned int*)(w + OFF_HIST);
    unsigned int* ccnt = (unsigned int*)(w + OFF_CCNT);
    unsigned int* selB = (unsigned int*)(w + OFF_SELB);
    unsigned long long* cbuf = (unsigned long long*)(w + OFF_CBUF);
    unsigned int* tidx = (unsigned int*)(w + OFF_TIDX);
    float* tscr = (float*)(w + OFF_TSCR);
    float* boxes = (float*)(w + OFF_BOX);
    float* corn = (float*)(w + OFF_CORN);
    float* area = (float*)(w + OFF_AREA);
    float* rad = (float*)(w + OFF_RAD);
    unsigned long long* vmask = (unsigned long long*)(w + OFF_VMSK);
    unsigned long long* masks = (unsigned long long*)(w + OFF_MASK);
    unsigned int* kept = (unsigned int*)(w + OFF_KEPT);
    unsigned int* kcnt = (unsigned int*)(w + OFF_KCNT);

    k_init<<<32, 256, 0, stream>>>(hist, ccnt);
    k_hist<<<(N_IMG * HW) / 256, 256, 0, stream>>>(obj, hist);
    k_findbin<<<N_IMG, 256, 0, stream>>>(hist, selB);
    k_compact<<<(N_IMG * HW) / 256, 256, 0, stream>>>(obj, selB, ccnt, cbuf);
    k_sort<<<N_IMG, 1024, 0, stream>>>(ccnt, cbuf, tidx, tscr);
    k_decode<<<N_IMG, 1024, 0, stream>>>(boxreg, tidx, tscr, boxes, corn, area, rad, vmask);
    k_iou<<<N_IMG * PRE, 256, 0, stream>>>(boxes, corn, area, rad, masks);
    k_nms<<<N_IMG, 64, 0, stream>>>(masks, vmask, kept, kcnt);
    k_out<<<N_IMG, POST, 0, stream>>>(boxes, tscr, kept, kcnt, out);
}

// Round 2
// 305.010 us; speedup vs baseline: 2.1464x; 2.1464x over previous
//
#include <hip/hip_runtime.h>
#include <hip/hip_bf16.h>

#define N_IMG 2
#define HH 256
#define WW 256
#define HW 65536
#define PRE 1024
#define POST 256
#define NBIN 4096
#define CAPC 8192
#define NMS_THR 0.7f
#define SCORE_T 0.1f
#define MIN_SZ 4.0f

// ---------- sortable key helpers ----------
__device__ __forceinline__ unsigned int fkey(float f) {
    unsigned int u = __float_as_uint(f);
    return u ^ ((u & 0x80000000u) ? 0xFFFFFFFFu : 0x80000000u);
}
__device__ __forceinline__ float unfkey(unsigned int k) {
    unsigned int u = (k & 0x80000000u) ? (k ^ 0x80000000u) : ~k;
    return __uint_as_float(u);
}

// ---------- kernels ----------
__global__ void k_init(unsigned int* hist, unsigned int* ccnt) {
    int t = blockIdx.x * blockDim.x + threadIdx.x;
    if (t < N_IMG * NBIN) hist[t] = 0u;
    if (t < N_IMG) ccnt[t] = 0u;
}

__global__ void k_hist(const float* __restrict__ obj, unsigned int* hist) {
    int g = blockIdx.x * blockDim.x + threadIdx.x;   // 0 .. N_IMG*HW-1
    int img = g >> 16;
    unsigned int key = fkey(obj[g]);
    atomicAdd(&hist[img * NBIN + (key >> 20)], 1u);
}

__global__ void k_findbin(const unsigned int* __restrict__ hist, unsigned int* selB) {
    __shared__ unsigned int lh[NBIN];
    __shared__ unsigned int chunk[256];
    int img = blockIdx.x;
    int t = threadIdx.x;
    unsigned int s = 0;
    for (int k = 0; k < 16; ++k) {
        unsigned int v = hist[img * NBIN + t * 16 + k];
        lh[t * 16 + k] = v;
        s += v;
    }
    chunk[t] = s;
    __syncthreads();
    if (t == 0) {
        unsigned int run = 0;
        int c;
        for (c = 255; c >= 0; --c) {
            if (run + chunk[c] >= PRE) break;
            run += chunk[c];
        }
        unsigned int B = 0;
        for (int b = c * 16 + 15; b >= c * 16; --b) {
            if (run + lh[b] >= PRE) { B = (unsigned int)b; break; }
            run += lh[b];
        }
        selB[img] = B;
    }
}

__global__ void k_compact(const float* __restrict__ obj, const unsigned int* __restrict__ selB,
                          unsigned int* ccnt, unsigned long long* cbuf) {
    int g = blockIdx.x * blockDim.x + threadIdx.x;
    int img = g >> 16;
    int e = g & 0xFFFF;
    unsigned int key = fkey(obj[g]);
    if ((key >> 20) >= selB[img]) {
        unsigned int pos = atomicAdd(&ccnt[img], 1u);
        if (pos < CAPC) {
            cbuf[img * CAPC + pos] =
                ((unsigned long long)key << 32) | (unsigned long long)(0xFFFFFFFFu - (unsigned int)e);
        }
    }
}

__global__ __launch_bounds__(1024) void k_sort(const unsigned int* __restrict__ ccnt,
                                               const unsigned long long* __restrict__ cbuf,
                                               unsigned int* tidx, float* tscr) {
    __shared__ unsigned long long sk[CAPC];   // 64 KB
    int img = blockIdx.x;
    int t = threadIdx.x;
    unsigned int M = ccnt[img];
    if (M > CAPC) M = CAPC;
    if (M < PRE) M = PRE;          // guaranteed by k_findbin; belt-and-braces
    unsigned int NP2 = 1;
    while (NP2 < M) NP2 <<= 1;     // sort only the occupied power-of-2 prefix
    for (unsigned int i = t; i < NP2; i += 1024)
        sk[i] = (i < M) ? cbuf[img * CAPC + i] : 0ULL;
    __syncthreads();
    for (unsigned int k = 2; k <= NP2; k <<= 1) {
        for (unsigned int j = k >> 1; j > 0; j >>= 1) {
            for (unsigned int i = t; i < NP2; i += 1024) {
                unsigned int ixj = i ^ j;
                if (ixj > i) {
                    unsigned long long a = sk[i], b = sk[ixj];
                    bool up = ((i & k) == 0);
                    if (up ? (a < b) : (a > b)) { sk[i] = b; sk[ixj] = a; }
                }
            }
            __syncthreads();
        }
    }
    if (t < PRE) {
        unsigned long long v = sk[t];
        unsigned int key = (unsigned int)(v >> 32);
        unsigned int idx = 0xFFFFFFFFu - (unsigned int)(v & 0xFFFFFFFFULL);
        tidx[img * PRE + t] = idx;
        tscr[img * PRE + t] = unfkey(key);
    }
}

__global__ __launch_bounds__(1024) void k_decode(const float* __restrict__ boxreg,
                                                 const unsigned int* __restrict__ tidx,
                                                 const float* __restrict__ tscr,
                                                 float* boxes, float* corn, float* area, float* rad,
                                                 unsigned long long* vmask) {
    int img = blockIdx.x;
    int r = threadIdx.x;
    unsigned int idx = tidx[img * PRE + r];
    float sc = tscr[img * PRE + r];
    int h = (int)(idx >> 8);
    int w = (int)(idx & 255u);
    const float* rg = boxreg + (size_t)img * 5 * HW;
    float t_ = rg[0 * HW + idx] * 1024.0f;
    float rr = rg[1 * HW + idx] * 1024.0f;
    float bb = rg[2 * HW + idx] * 1024.0f;
    float ll = rg[3 * HW + idx] * 1024.0f;
    float ang = (rg[4 * HW + idx] - 0.5f) * 90.0f;
    float wd = ll + rr;
    float ht = t_ + bb;
    float xc = (float)w * 4.0f + 0.5f * (rr - ll);
    float yc = (float)h * 4.0f + 0.5f * (bb - t_);
    xc = fminf(fmaxf(xc, 0.0f), 1023.0f);
    yc = fminf(fmaxf(yc, 0.0f), 1023.0f);
    bool valid = (sc > SCORE_T) && (wd >= MIN_SZ) && (ht >= MIN_SZ);

    float* bx = boxes + (size_t)(img * PRE + r) * 5;
    bx[0] = xc; bx[1] = yc; bx[2] = wd; bx[3] = ht; bx[4] = ang;

    float th = ang * (float)(3.14159265358979323846 / 180.0);
    float c = cosf(th), s = sinf(th);
    const float dxs[4] = {-0.5f, 0.5f, 0.5f, -0.5f};
    const float dys[4] = {-0.5f, -0.5f, 0.5f, 0.5f};
    float* cr = corn + (size_t)(img * PRE + r) * 8;
#pragma unroll
    for (int k = 0; k < 4; ++k) {
        float dx = dxs[k] * wd, dy = dys[k] * ht;
        cr[2 * k]     = xc + dx * c - dy * s;
        cr[2 * k + 1] = yc + dx * s + dy * c;
    }
    area[img * PRE + r] = wd * ht;
    rad[img * PRE + r] = 0.5f * sqrtf(wd * wd + ht * ht) + 0.01f;  // tiny safety margin

    unsigned long long bal = __ballot(valid ? 1 : 0);
    if ((threadIdx.x & 63) == 0) vmask[img * 16 + (threadIdx.x >> 6)] = bal;
}

// Sutherland-Hodgman convex clip of quad A against quad B edges; mirrors reference math.
__device__ float inter_area(const float* pax, const float* pay, const float* __restrict__ cb) {
    float px[8], py[8], qx[8], qy[8];
    int n = 4;
#pragma unroll
    for (int k = 0; k < 4; ++k) { px[k] = pax[k]; py[k] = pay[k]; }
    for (int e = 0; e < 4; ++e) {
        float p1x = cb[2 * e], p1y = cb[2 * e + 1];
        int e2 = (e + 1) & 3;
        float ex = cb[2 * e2] - p1x, ey = cb[2 * e2 + 1] - p1y;
        int m = 0;
        for (int k = 0; k < n; ++k) {
            int kn = (k + 1 < n) ? k + 1 : 0;
            float dc = ex * (py[k] - p1y) - ey * (px[k] - p1x);
            float dn = ex * (py[kn] - p1y) - ey * (px[kn] - p1x);
            bool ic = dc >= 0.0f;
            bool inx = dn >= 0.0f;
            if (ic && m < 8) { qx[m] = px[k]; qy[m] = py[k]; ++m; }
            if ((ic != inx) && m < 8) {
                float den = dc - dn;
                float safe = (fabsf(den) > 1e-9f) ? den : 1.0f;
                float tt = dc / safe;
                qx[m] = px[k] + tt * (px[kn] - px[k]);
                qy[m] = py[k] + tt * (py[kn] - py[k]);
                ++m;
            }
        }
        n = m;
        for (int k = 0; k < n; ++k) { px[k] = qx[k]; py[k] = qy[k]; }
    }
    if (n < 3) return 0.0f;
    float s = 0.0f;
    for (int k = 0; k < n; ++k) {
        int kn = (k + 1 < n) ? k + 1 : 0;
        s += px[k] * py[kn] - px[kn] * py[k];
    }
    return 0.5f * fabsf(s);
}

__global__ __launch_bounds__(256) void k_iou(const float* __restrict__ boxes,
                                             const float* __restrict__ corn,
                                             const float* __restrict__ area,
                                             const float* __restrict__ rad,
                                             unsigned long long* masks) {
    int row = blockIdx.x;          // 0 .. N_IMG*PRE-1
    int img = row >> 10;
    int i = row & 1023;
    __shared__ float pax[4], pay[4], sArA, sCxA, sCyA, sRA;
    if (threadIdx.x == 0) {
        const float* cr = corn + (size_t)row * 8;
#pragma unroll
        for (int k = 0; k < 4; ++k) { pax[k] = cr[2 * k]; pay[k] = cr[2 * k + 1]; }
        sArA = area[row];
        const float* b = boxes + (size_t)row * 5;
        sCxA = b[0]; sCyA = b[1];
        sRA = rad[row];
    }
    __syncthreads();
    for (int c = 0; c < 4; ++c) {
        int j = c * 256 + threadIdx.x;
        bool flag = false;
        if (j > i) {
            int col = img * PRE + j;
            float dx = boxes[(size_t)col * 5 + 0] - sCxA;
            float dy = boxes[(size_t)col * 5 + 1] - sCyA;
            float rr = sRA + rad[col];
            if (dx * dx + dy * dy <= rr * rr) {
                const float* cbp = corn + (size_t)col * 8;
                float inter = inter_area(pax, pay, cbp);
                float uni = sArA + area[col] - inter;
                float iou = inter / fmaxf(uni, 1e-9f);
                flag = iou > NMS_THR;
            }
        }
        unsigned long long bal = __ballot(flag ? 1 : 0);
        if ((threadIdx.x & 63) == 0)
            masks[(size_t)row * 16 + c * 4 + (threadIdx.x >> 6)] = bal;
    }
}

// Sequential greedy NMS, one wave per image, with 16-deep register prefetch of the
// mask rows (loads never sit on the dependent chain), fused with output emission.
__global__ __launch_bounds__(64) void k_nms_out(const unsigned long long* __restrict__ masks,
                                                const unsigned long long* __restrict__ vmask,
                                                const float* __restrict__ boxes,
                                                const float* __restrict__ tscr,
                                                float* __restrict__ out) {
    int img = blockIdx.x;
    int lane = threadIdx.x;                 // 0..63, one wave
    __shared__ unsigned short keptIdx[POST];
    unsigned long long sup = 0ULL;
    unsigned long long vw = (lane < 16) ? vmask[img * 16 + lane] : 0ULL;
    const unsigned long long* mbase = masks + (size_t)img * PRE * 16;

    unsigned long long buf[16];
#pragma unroll
    for (int d = 0; d < 16; ++d)
        buf[d] = (lane < 16) ? mbase[(size_t)d * 16 + lane] : 0ULL;

    int cnt = 0;
    for (int o = 0; o < 16; ++o) {          // owner lane o covers rows o*64 .. o*64+63
#pragma unroll
        for (int d = 0; d < 64; ++d) {
            int i = o * 64 + d;
            // only lane o's value matters; readlane broadcasts it (SALU, uniform o)
            int my = (int)((vw >> d) & 1ULL) & (int)((~(sup >> d)) & 1ULL);
            int kflag = __builtin_amdgcn_readlane(my, o);
            unsigned long long m = buf[d & 15];          // row i (loaded 16 iters ago)
            int pf = i + 16; if (pf > PRE - 1) pf = PRE - 1;
            buf[d & 15] = (lane < 16) ? mbase[(size_t)pf * 16 + lane] : 0ULL;
            sup |= kflag ? m : 0ULL;
            if (kflag) {                                  // uniform branch
                if (lane == 0 && cnt < POST) keptIdx[cnt] = (unsigned short)i;
                ++cnt;
            }
        }
    }
    __syncthreads();
    int total = (cnt > POST) ? POST : cnt;
#pragma unroll
    for (int q = 0; q < POST / 64; ++q) {
        int r = q * 64 + lane;
        float v0 = 0.f, v1 = 0.f, v2 = 0.f, v3 = 0.f, v4 = 0.f, v5 = 0.f;
        if (r < total) {
            int i = keptIdx[r];
            const float* b = boxes + (size_t)(img * PRE + i) * 5;
            v0 = b[0]; v1 = b[1]; v2 = b[2]; v3 = b[3]; v4 = b[4];
            v5 = tscr[img * PRE + i];
        }
        float* o2 = out + (size_t)(img * POST + r) * 6;
        o2[0] = v0; o2[1] = v1; o2[2] = v2; o2[3] = v3; o2[4] = v4; o2[5] = v5;
    }
}

// ---------- workspace layout (all offsets 8-byte aligned) ----------
enum : size_t {
    OFF_HIST = 0,          // 2*4096*4  = 32768
    OFF_CCNT = 32768,      // 8
    OFF_SELB = 32776,      // 8
    OFF_CBUF = 32784,      // 2*8192*8  = 131072 -> 163856
    OFF_TIDX = 163856,     // 8192 -> 172048
    OFF_TSCR = 172048,     // 8192 -> 180240
    OFF_BOX  = 180240,     // 40960 -> 221200
    OFF_CORN = 221200,     // 65536 -> 286736
    OFF_AREA = 286736,     // 8192 -> 294928
    OFF_RAD  = 294928,     // 8192 -> 303120
    OFF_VMSK = 303120,     // 256 -> 303376
    OFF_MASK = 303376,     // 262144 -> 565520
};

extern "C" void kernel_launch(void* const* d_in, const int* in_sizes, int n_in,
                              void* d_out, int out_size, void* d_ws, size_t ws_size,
                              hipStream_t stream) {
    const float* obj = (const float*)d_in[0];       // (2,1,256,256) f32
    const float* boxreg = (const float*)d_in[1];    // (2,5,256,256) f32
    float* out = (float*)d_out;                     // (2,256,6) f32

    char* w = (char*)d_ws;
    unsigned int* hist = (unsigned int*)(w + OFF_HIST);
    unsigned int* ccnt = (unsigned int*)(w + OFF_CCNT);
    unsigned int* selB = (unsigned int*)(w + OFF_SELB);
    unsigned long long* cbuf = (unsigned long long*)(w + OFF_CBUF);
    unsigned int* tidx = (unsigned int*)(w + OFF_TIDX);
    float* tscr = (float*)(w + OFF_TSCR);
    float* boxes = (float*)(w + OFF_BOX);
    float* corn = (float*)(w + OFF_CORN);
    float* area = (float*)(w + OFF_AREA);
    float* rad = (float*)(w + OFF_RAD);
    unsigned long long* vmask = (unsigned long long*)(w + OFF_VMSK);
    unsigned long long* masks = (unsigned long long*)(w + OFF_MASK);

    k_init<<<32, 256, 0, stream>>>(hist, ccnt);
    k_hist<<<(N_IMG * HW) / 256, 256, 0, stream>>>(obj, hist);
    k_findbin<<<N_IMG, 256, 0, stream>>>(hist, selB);
    k_compact<<<(N_IMG * HW) / 256, 256, 0, stream>>>(obj, selB, ccnt, cbuf);
    k_sort<<<N_IMG, 1024, 0, stream>>>(ccnt, cbuf, tidx, tscr);
    k_decode<<<N_IMG, 1024, 0, stream>>>(boxreg, tidx, tscr, boxes, corn, area, rad, vmask);
    k_iou<<<N_IMG * PRE, 256, 0, stream>>>(boxes, corn, area, rad, masks);
    k_nms_out<<<N_IMG, 64, 0, stream>>>(masks, vmask, boxes, tscr, out);
}

// Round 3
// 285.575 us; speedup vs baseline: 2.2925x; 1.0681x over previous
//
#include <hip/hip_runtime.h>
#include <hip/hip_bf16.h>

#define N_IMG 2
#define HH 256
#define WW 256
#define HW 65536
#define PRE 1024
#define POST 256
#define NBIN 4096
#define CAPC 8192
#define NMS_THR 0.7f
#define SCORE_T 0.1f
#define MIN_SZ 4.0f

// ---------- sortable key helpers ----------
__device__ __forceinline__ unsigned int fkey(float f) {
    unsigned int u = __float_as_uint(f);
    return u ^ ((u & 0x80000000u) ? 0xFFFFFFFFu : 0x80000000u);
}
__device__ __forceinline__ float unfkey(unsigned int k) {
    unsigned int u = (k & 0x80000000u) ? (k ^ 0x80000000u) : ~k;
    return __uint_as_float(u);
}

// ---------- kernels ----------
__global__ void k_init(unsigned int* hist, unsigned int* ccnt) {
    int t = blockIdx.x * blockDim.x + threadIdx.x;
    if (t < N_IMG * NBIN) hist[t] = 0u;
    if (t < N_IMG) ccnt[t] = 0u;
}

__global__ void k_hist(const float* __restrict__ obj, unsigned int* hist) {
    int g = blockIdx.x * blockDim.x + threadIdx.x;   // 0 .. N_IMG*HW-1
    int img = g >> 16;
    unsigned int key = fkey(obj[g]);
    atomicAdd(&hist[img * NBIN + (key >> 20)], 1u);
}

__global__ void k_findbin(const unsigned int* __restrict__ hist, unsigned int* selB) {
    __shared__ unsigned int lh[NBIN];
    __shared__ unsigned int chunk[256];
    int img = blockIdx.x;
    int t = threadIdx.x;
    unsigned int s = 0;
    for (int k = 0; k < 16; ++k) {
        unsigned int v = hist[img * NBIN + t * 16 + k];
        lh[t * 16 + k] = v;
        s += v;
    }
    chunk[t] = s;
    __syncthreads();
    if (t == 0) {
        unsigned int run = 0;
        int c;
        for (c = 255; c >= 0; --c) {
            if (run + chunk[c] >= PRE) break;
            run += chunk[c];
        }
        unsigned int B = 0;
        for (int b = c * 16 + 15; b >= c * 16; --b) {
            if (run + lh[b] >= PRE) { B = (unsigned int)b; break; }
            run += lh[b];
        }
        selB[img] = B;
    }
}

__global__ void k_compact(const float* __restrict__ obj, const unsigned int* __restrict__ selB,
                          unsigned int* ccnt, unsigned long long* cbuf) {
    int g = blockIdx.x * blockDim.x + threadIdx.x;
    int img = g >> 16;
    int e = g & 0xFFFF;
    unsigned int key = fkey(obj[g]);
    if ((key >> 20) >= selB[img]) {
        unsigned int pos = atomicAdd(&ccnt[img], 1u);
        if (pos < CAPC) {
            cbuf[img * CAPC + pos] =
                ((unsigned long long)key << 32) | (unsigned long long)(0xFFFFFFFFu - (unsigned int)e);
        }
    }
}

__global__ __launch_bounds__(1024) void k_sort(const unsigned int* __restrict__ ccnt,
                                               const unsigned long long* __restrict__ cbuf,
                                               unsigned int* tidx, float* tscr) {
    __shared__ unsigned long long sk[CAPC];   // 64 KB
    int img = blockIdx.x;
    int t = threadIdx.x;
    unsigned int M = ccnt[img];
    if (M > CAPC) M = CAPC;
    if (M < PRE) M = PRE;          // guaranteed by k_findbin; belt-and-braces
    unsigned int NP2 = 1;
    while (NP2 < M) NP2 <<= 1;     // sort only the occupied power-of-2 prefix
    for (unsigned int i = t; i < NP2; i += 1024)
        sk[i] = (i < M) ? cbuf[img * CAPC + i] : 0ULL;
    __syncthreads();
    for (unsigned int k = 2; k <= NP2; k <<= 1) {
        for (unsigned int j = k >> 1; j > 0; j >>= 1) {
            for (unsigned int i = t; i < NP2; i += 1024) {
                unsigned int ixj = i ^ j;
                if (ixj > i) {
                    unsigned long long a = sk[i], b = sk[ixj];
                    bool up = ((i & k) == 0);
                    if (up ? (a < b) : (a > b)) { sk[i] = b; sk[ixj] = a; }
                }
            }
            __syncthreads();
        }
    }
    if (t < PRE) {
        unsigned long long v = sk[t];
        unsigned int key = (unsigned int)(v >> 32);
        unsigned int idx = 0xFFFFFFFFu - (unsigned int)(v & 0xFFFFFFFFULL);
        tidx[img * PRE + t] = idx;
        tscr[img * PRE + t] = unfkey(key);
    }
}

__global__ __launch_bounds__(1024) void k_decode(const float* __restrict__ boxreg,
                                                 const unsigned int* __restrict__ tidx,
                                                 const float* __restrict__ tscr,
                                                 float* boxes, float* corn, float* area, float* rad,
                                                 unsigned long long* vmask) {
    int img = blockIdx.x;
    int r = threadIdx.x;
    unsigned int idx = tidx[img * PRE + r];
    float sc = tscr[img * PRE + r];
    int h = (int)(idx >> 8);
    int w = (int)(idx & 255u);
    const float* rg = boxreg + (size_t)img * 5 * HW;
    float t_ = rg[0 * HW + idx] * 1024.0f;
    float rr = rg[1 * HW + idx] * 1024.0f;
    float bb = rg[2 * HW + idx] * 1024.0f;
    float ll = rg[3 * HW + idx] * 1024.0f;
    float ang = (rg[4 * HW + idx] - 0.5f) * 90.0f;
    float wd = ll + rr;
    float ht = t_ + bb;
    float xc = (float)w * 4.0f + 0.5f * (rr - ll);
    float yc = (float)h * 4.0f + 0.5f * (bb - t_);
    xc = fminf(fmaxf(xc, 0.0f), 1023.0f);
    yc = fminf(fmaxf(yc, 0.0f), 1023.0f);
    bool valid = (sc > SCORE_T) && (wd >= MIN_SZ) && (ht >= MIN_SZ);

    float* bx = boxes + (size_t)(img * PRE + r) * 5;
    bx[0] = xc; bx[1] = yc; bx[2] = wd; bx[3] = ht; bx[4] = ang;

    float th = ang * (float)(3.14159265358979323846 / 180.0);
    float c = cosf(th), s = sinf(th);
    const float dxs[4] = {-0.5f, 0.5f, 0.5f, -0.5f};
    const float dys[4] = {-0.5f, -0.5f, 0.5f, 0.5f};
    float* cr = corn + (size_t)(img * PRE + r) * 8;
#pragma unroll
    for (int k = 0; k < 4; ++k) {
        float dx = dxs[k] * wd, dy = dys[k] * ht;
        cr[2 * k]     = xc + dx * c - dy * s;
        cr[2 * k + 1] = yc + dx * s + dy * c;
    }
    area[img * PRE + r] = wd * ht;
    rad[img * PRE + r] = 0.5f * sqrtf(wd * wd + ht * ht) + 0.01f;  // tiny safety margin

    unsigned long long bal = __ballot(valid ? 1 : 0);
    if ((threadIdx.x & 63) == 0) vmask[img * 16 + (threadIdx.x >> 6)] = bal;
}

// Sutherland-Hodgman convex clip of quad A against quad B edges; mirrors reference math.
__device__ float inter_area(const float* pax, const float* pay, const float* __restrict__ cb) {
    float px[8], py[8], qx[8], qy[8];
    int n = 4;
#pragma unroll
    for (int k = 0; k < 4; ++k) { px[k] = pax[k]; py[k] = pay[k]; }
    for (int e = 0; e < 4; ++e) {
        float p1x = cb[2 * e], p1y = cb[2 * e + 1];
        int e2 = (e + 1) & 3;
        float ex = cb[2 * e2] - p1x, ey = cb[2 * e2 + 1] - p1y;
        int m = 0;
        for (int k = 0; k < n; ++k) {
            int kn = (k + 1 < n) ? k + 1 : 0;
            float dc = ex * (py[k] - p1y) - ey * (px[k] - p1x);
            float dn = ex * (py[kn] - p1y) - ey * (px[kn] - p1x);
            bool ic = dc >= 0.0f;
            bool inx = dn >= 0.0f;
            if (ic && m < 8) { qx[m] = px[k]; qy[m] = py[k]; ++m; }
            if ((ic != inx) && m < 8) {
                float den = dc - dn;
                float safe = (fabsf(den) > 1e-9f) ? den : 1.0f;
                float tt = dc / safe;
                qx[m] = px[k] + tt * (px[kn] - px[k]);
                qy[m] = py[k] + tt * (py[kn] - py[k]);
                ++m;
            }
        }
        n = m;
        for (int k = 0; k < n; ++k) { px[k] = qx[k]; py[k] = qy[k]; }
    }
    if (n < 3) return 0.0f;
    float s = 0.0f;
    for (int k = 0; k < n; ++k) {
        int kn = (k + 1 < n) ? k + 1 : 0;
        s += px[k] * py[kn] - px[kn] * py[k];
    }
    return 0.5f * fabsf(s);
}

__global__ __launch_bounds__(256) void k_iou(const float* __restrict__ boxes,
                                             const float* __restrict__ corn,
                                             const float* __restrict__ area,
                                             const float* __restrict__ rad,
                                             unsigned long long* masks) {
    int row = blockIdx.x;          // 0 .. N_IMG*PRE-1
    int img = row >> 10;
    int i = row & 1023;
    __shared__ float pax[4], pay[4], sArA, sCxA, sCyA, sRA;
    if (threadIdx.x == 0) {
        const float* cr = corn + (size_t)row * 8;
#pragma unroll
        for (int k = 0; k < 4; ++k) { pax[k] = cr[2 * k]; pay[k] = cr[2 * k + 1]; }
        sArA = area[row];
        const float* b = boxes + (size_t)row * 5;
        sCxA = b[0]; sCyA = b[1];
        sRA = rad[row];
    }
    __syncthreads();
    for (int c = 0; c < 4; ++c) {
        int j = c * 256 + threadIdx.x;
        bool flag = false;
        if (j > i) {
            int col = img * PRE + j;
            float dx = boxes[(size_t)col * 5 + 0] - sCxA;
            float dy = boxes[(size_t)col * 5 + 1] - sCyA;
            float rr = sRA + rad[col];
            if (dx * dx + dy * dy <= rr * rr) {
                const float* cbp = corn + (size_t)col * 8;
                float inter = inter_area(pax, pay, cbp);
                float uni = sArA + area[col] - inter;
                float iou = inter / fmaxf(uni, 1e-9f);
                flag = iou > NMS_THR;
            }
        }
        unsigned long long bal = __ballot(flag ? 1 : 0);
        if ((threadIdx.x & 63) == 0)
            masks[(size_t)row * 16 + c * 4 + (threadIdx.x >> 6)] = bal;
    }
}

// Sequential greedy NMS, one wave per image. 32-deep rolling register prefetch with
// UNCONDITIONAL loads (no select on the load result -> waitcnt stays deferred to use),
// and a pure-SALU keep-test chain: per 64-row group, avail = valid & ~sup for the
// group's word lives in an SGPR pair; memory waits occur only on kept rows (~76/1024).
__global__ __launch_bounds__(64) void k_nms_out(const unsigned long long* __restrict__ masks,
                                                const unsigned long long* __restrict__ vmask,
                                                const float* __restrict__ boxes,
                                                const float* __restrict__ tscr,
                                                float* __restrict__ out) {
    int img = blockIdx.x;
    int lane = threadIdx.x;                 // 0..63, one wave
    int lw = lane & 15;                     // mask word this lane mirrors (4 copies)
    __shared__ unsigned short keptIdx[POST];
    const unsigned long long* mbase = masks + (size_t)img * PRE * 16;

    unsigned long long vw = vmask[img * 16 + lw];
    unsigned long long sup = 0ULL;

    unsigned long long buf[32];
#pragma unroll
    for (int d = 0; d < 32; ++d)
        buf[d] = mbase[(size_t)d * 16 + lw];

    int cnt = 0;
    for (int o = 0; o < 16; ++o) {          // rows o*64 .. o*64+63; their sup word is #o
        unsigned long long kv =
            ((unsigned long long)(unsigned int)__builtin_amdgcn_readlane((int)(vw >> 32), o) << 32) |
            (unsigned long long)(unsigned int)__builtin_amdgcn_readlane((int)(unsigned int)vw, o);
        unsigned long long sc =
            ((unsigned long long)(unsigned int)__builtin_amdgcn_readlane((int)(sup >> 32), o) << 32) |
            (unsigned long long)(unsigned int)__builtin_amdgcn_readlane((int)(unsigned int)sup, o);
        unsigned long long avail = kv & ~sc;    // SGPR pair: rows of this group still eligible
#pragma unroll
        for (int d = 0; d < 64; ++d) {
            int i = o * 64 + d;
            unsigned long long m = buf[i & 31];              // row i (issued 32 iters ago)
            int pf = i + 32; if (pf > PRE - 1) pf = PRE - 1;
            buf[i & 31] = mbase[(size_t)pf * 16 + lw];       // unconditional prefetch
            if ((avail >> d) & 1ULL) {                        // scalar branch, rarely taken
                sup |= m;                                     // vector update (all word copies)
                unsigned long long mo =
                    ((unsigned long long)(unsigned int)__builtin_amdgcn_readlane((int)(m >> 32), o) << 32) |
                    (unsigned long long)(unsigned int)__builtin_amdgcn_readlane((int)(unsigned int)m, o);
                avail &= ~mo;                                 // suppress within this group
                if (lane == 0 && cnt < POST) keptIdx[cnt] = (unsigned short)i;
                ++cnt;
            }
        }
    }
    __syncthreads();
    int total = (cnt > POST) ? POST : cnt;
#pragma unroll
    for (int q = 0; q < POST / 64; ++q) {
        int r = q * 64 + lane;
        float v0 = 0.f, v1 = 0.f, v2 = 0.f, v3 = 0.f, v4 = 0.f, v5 = 0.f;
        if (r < total) {
            int i = keptIdx[r];
            const float* b = boxes + (size_t)(img * PRE + i) * 5;
            v0 = b[0]; v1 = b[1]; v2 = b[2]; v3 = b[3]; v4 = b[4];
            v5 = tscr[img * PRE + i];
        }
        float* o2 = out + (size_t)(img * POST + r) * 6;
        o2[0] = v0; o2[1] = v1; o2[2] = v2; o2[3] = v3; o2[4] = v4; o2[5] = v5;
    }
}

// ---------- workspace layout (all offsets 8-byte aligned) ----------
enum : size_t {
    OFF_HIST = 0,          // 2*4096*4  = 32768
    OFF_CCNT = 32768,      // 8
    OFF_SELB = 32776,      // 8
    OFF_CBUF = 32784,      // 2*8192*8  = 131072 -> 163856
    OFF_TIDX = 163856,     // 8192 -> 172048
    OFF_TSCR = 172048,     // 8192 -> 180240
    OFF_BOX  = 180240,     // 40960 -> 221200
    OFF_CORN = 221200,     // 65536 -> 286736
    OFF_AREA = 286736,     // 8192 -> 294928
    OFF_RAD  = 294928,     // 8192 -> 303120
    OFF_VMSK = 303120,     // 256 -> 303376
    OFF_MASK = 303376,     // 262144 -> 565520
};

extern "C" void kernel_launch(void* const* d_in, const int* in_sizes, int n_in,
                              void* d_out, int out_size, void* d_ws, size_t ws_size,
                              hipStream_t stream) {
    const float* obj = (const float*)d_in[0];       // (2,1,256,256) f32
    const float* boxreg = (const float*)d_in[1];    // (2,5,256,256) f32
    float* out = (float*)d_out;                     // (2,256,6) f32

    char* w = (char*)d_ws;
    unsigned int* hist = (unsigned int*)(w + OFF_HIST);
    unsigned int* ccnt = (unsigned int*)(w + OFF_CCNT);
    unsigned int* selB = (unsigned int*)(w + OFF_SELB);
    unsigned long long* cbuf = (unsigned long long*)(w + OFF_CBUF);
    unsigned int* tidx = (unsigned int*)(w + OFF_TIDX);
    float* tscr = (float*)(w + OFF_TSCR);
    float* boxes = (float*)(w + OFF_BOX);
    float* corn = (float*)(w + OFF_CORN);
    float* area = (float*)(w + OFF_AREA);
    float* rad = (float*)(w + OFF_RAD);
    unsigned long long* vmask = (unsigned long long*)(w + OFF_VMSK);
    unsigned long long* masks = (unsigned long long*)(w + OFF_MASK);

    k_init<<<32, 256, 0, stream>>>(hist, ccnt);
    k_hist<<<(N_IMG * HW) / 256, 256, 0, stream>>>(obj, hist);
    k_findbin<<<N_IMG, 256, 0, stream>>>(hist, selB);
    k_compact<<<(N_IMG * HW) / 256, 256, 0, stream>>>(obj, selB, ccnt, cbuf);
    k_sort<<<N_IMG, 1024, 0, stream>>>(ccnt, cbuf, tidx, tscr);
    k_decode<<<N_IMG, 1024, 0, stream>>>(boxreg, tidx, tscr, boxes, corn, area, rad, vmask);
    k_iou<<<N_IMG * PRE, 256, 0, stream>>>(boxes, corn, area, rad, masks);
    k_nms_out<<<N_IMG, 64, 0, stream>>>(masks, vmask, boxes, tscr, out);
}